// Round 4
// baseline (384.703 us; speedup 1.0000x reference)
//
#include <hip/hip_runtime.h>

// GNN_17575006175684: 3-layer GCN + mean-pool + linear head + log_softmax.
// R4: CSR build via hierarchical counting sort:
//   csort_count  -> per-(chunk,slice) histogram (slices = dst>>13, ~13 of them)
//   csort_scan   -> exclusive scan (slice-major) => exact scatter offsets, no
//                   global atomics in the scatter
//   csort_scatter-> (dst,src) bucketed slice-major, edge stream read ONCE
//   deg_bucket   -> node-degree histogram, per-slice teams, L2-local atomics
//   scan1..3     -> row_ptr (dinv fused into scan1)
//   fill_bucket  -> CSR col fill; cursor+col windows are slice-local (CSR is
//                   dst-ordered so col positions for slice s lie in
//                   [sliceBeg[s], sliceBeg[s+1]) -- same XCD's L2)
// Layers unchanged from R3 (gather-before-transform, fused matmul epilogue),
// pool+head atomic-free.

#define BLK 256
#define CHUNK 1024          // edges per counting-sort chunk (1 block each)
#define SLICE_SHIFT 13      // slice = dst >> 13  (8192 nodes/slice)
#define NS_MAX 32

// ---------------- counting sort (bucket by dst-slice) ----------------

__global__ void csort_count(const int* __restrict__ dst, int* __restrict__ cnt,
                            int E, int nChunks, int NS) {
    __shared__ int h[NS_MAX];
    int b = blockIdx.x, t = threadIdx.x;
    if (t < NS) h[t] = 0;
    __syncthreads();
    int base = b * CHUNK;
#pragma unroll
    for (int j = 0; j < CHUNK / BLK; ++j) {
        int e = base + j * BLK + t;
        if (e < E) atomicAdd(&h[dst[e] >> SLICE_SHIFT], 1);
    }
    __syncthreads();
    if (t < NS) cnt[(size_t)t * nChunks + b] = h[t];   // slice-major
}

// single block: in-place exclusive scan of cnt[M]; emit sliceBeg[0..NS]
__global__ void csort_scan(int* __restrict__ cnt, int* __restrict__ sliceBeg,
                           int M, int NS, int nChunks, int E) {
    __shared__ int part[256];
    int t = threadIdx.x;
    int per = (M + 255) / 256;
    int lo = t * per, hi = lo + per < M ? lo + per : M;
    int sum = 0;
    for (int i = lo; i < hi; ++i) sum += cnt[i];
    part[t] = sum;
    __syncthreads();
    for (int off = 1; off < 256; off <<= 1) {
        int x = (t >= off) ? part[t - off] : 0;
        __syncthreads();
        if (t >= off) part[t] += x;
        __syncthreads();
    }
    int run = part[t] - sum;   // exclusive
    for (int i = lo; i < hi; ++i) { int v = cnt[i]; cnt[i] = run; run += v; }
    __syncthreads();
    if (t < NS) sliceBeg[t] = cnt[(size_t)t * nChunks];
    if (t == 0) sliceBeg[NS] = E;
}

__global__ void csort_scatter(const int* __restrict__ src, const int* __restrict__ dst,
                              const int* __restrict__ off, int* __restrict__ bd,
                              int* __restrict__ bs, int E, int nChunks, int NS) {
    __shared__ int lcnt[NS_MAX];
    __shared__ int lbase[NS_MAX];
    int b = blockIdx.x, t = threadIdx.x;
    if (t < NS) lcnt[t] = 0;
    __syncthreads();
    int base = b * CHUNK;
    int d[CHUNK / BLK], s[CHUNK / BLK], r[CHUNK / BLK], sl[CHUNK / BLK];
#pragma unroll
    for (int j = 0; j < CHUNK / BLK; ++j) {
        int e = base + j * BLK + t;
        bool ok = e < E;
        d[j] = ok ? dst[e] : 0;
        s[j] = ok ? src[e] : 0;
        sl[j] = d[j] >> SLICE_SHIFT;
        r[j] = ok ? atomicAdd(&lcnt[sl[j]], 1) : -1;
    }
    __syncthreads();
    if (t < NS) lbase[t] = off[(size_t)t * nChunks + b];
    __syncthreads();
#pragma unroll
    for (int j = 0; j < CHUNK / BLK; ++j) {
        if (r[j] >= 0) {
            int p = lbase[sl[j]] + r[j];
            bd[p] = d[j];
            bs[p] = s[j];
        }
    }
}

// per-slice teams: blockIdx%8 -> XCD locality heuristic (correctness-neutral)
__global__ void deg_bucket(const int* __restrict__ bd, const int* __restrict__ sliceBeg,
                           int* __restrict__ deg, int NS) {
    int xcd = blockIdx.x & 7;
    int sub = blockIdx.x >> 3;
    int nsub = gridDim.x >> 3;
    for (int s = xcd; s < NS; s += 8) {
        int lo = sliceBeg[s], hi = sliceBeg[s + 1];
        for (int e = lo + sub * BLK + threadIdx.x; e < hi; e += nsub * BLK)
            atomicAdd(&deg[bd[e]], 1);
    }
}

__global__ void fill_bucket(const int* __restrict__ bd, const int* __restrict__ bs,
                            const int* __restrict__ sliceBeg, int* __restrict__ cursor,
                            int* __restrict__ col, int NS) {
    int xcd = blockIdx.x & 7;
    int sub = blockIdx.x >> 3;
    int nsub = gridDim.x >> 3;
    for (int s = xcd; s < NS; s += 8) {
        int lo = sliceBeg[s], hi = sliceBeg[s + 1];
        for (int e = lo + sub * BLK + threadIdx.x; e < hi; e += nsub * BLK) {
            int p = atomicAdd(&cursor[bd[e]], 1);
            col[p] = bs[e];
        }
    }
}

// ---------------- row_ptr scan (dinv fused into scan1) ----------------

__global__ void scan1_kernel(const int* __restrict__ deg, float* __restrict__ dinv,
                             int* __restrict__ row_local, int* __restrict__ partials, int N) {
    __shared__ int sdata[256];
    int base = blockIdx.x * 1024;
    int t = threadIdx.x;
    int v[4];
    int sum = 0;
#pragma unroll
    for (int j = 0; j < 4; ++j) {
        int i = base + t * 4 + j;
        v[j] = (i < N) ? deg[i] : 0;
        if (i < N) dinv[i] = rsqrtf((float)v[j] + 1.0f);   // +1 self-loop
        sum += v[j];
    }
    sdata[t] = sum;
    __syncthreads();
    for (int off = 1; off < 256; off <<= 1) {
        int x = (t >= off) ? sdata[t - off] : 0;
        __syncthreads();
        if (t >= off) sdata[t] += x;
        __syncthreads();
    }
    int excl = sdata[t] - sum;
    if (t == 255) partials[blockIdx.x] = sdata[255];
    int run = excl;
#pragma unroll
    for (int j = 0; j < 4; ++j) {
        int i = base + t * 4 + j;
        if (i < N) { row_local[i] = run; run += v[j]; }
    }
}

__global__ void scan2_kernel(int* __restrict__ partials, int nb) {
    __shared__ int sdata[256];
    int t = threadIdx.x;
    int v = (t < nb) ? partials[t] : 0;
    sdata[t] = v;
    __syncthreads();
    for (int off = 1; off < 256; off <<= 1) {
        int x = (t >= off) ? sdata[t - off] : 0;
        __syncthreads();
        if (t >= off) sdata[t] += x;
        __syncthreads();
    }
    if (t < nb) partials[t] = sdata[t] - v;   // exclusive
}

__global__ void scan3_kernel(int* __restrict__ row_ptr, const int* __restrict__ partials,
                             int* __restrict__ cursor, int N, int E) {
    int i = blockIdx.x * blockDim.x + threadIdx.x;
    if (i < N) {
        int v = row_ptr[i] + partials[i >> 10];
        row_ptr[i] = v;
        cursor[i] = v;
    }
    if (i == 0) row_ptr[N] = E;
}

// ---------------- layers ----------------

__global__ void prescale1_kernel(const float* __restrict__ x, const float* __restrict__ dinv,
                                 float* __restrict__ xs, int N) {
    int idx = blockIdx.x * blockDim.x + threadIdx.x;
    if (idx >= N * 5) return;
    int n = idx / 5;
    xs[idx] = x[idx] * dinv[n];
}

template <int F>
__global__ void gather_kernel(const int* __restrict__ row_ptr, const int* __restrict__ col,
                              const float* __restrict__ xs, float* __restrict__ g, int N) {
    int idx = blockIdx.x * blockDim.x + threadIdx.x;
    if (idx >= N * F) return;
    int n = idx / F, f = idx % F;
    int beg = row_ptr[n], end = row_ptr[n + 1];
    float acc = xs[idx];
    int e = beg;
    for (; e + 3 < end; e += 4) {
        int s0 = col[e], s1 = col[e + 1], s2 = col[e + 2], s3 = col[e + 3];
        float a = xs[s0 * F + f], b = xs[s1 * F + f];
        float c = xs[s2 * F + f], d = xs[s3 * F + f];
        acc += a + b + c + d;
    }
    for (; e < end; ++e) acc += xs[col[e] * F + f];
    g[idx] = acc;
}

template <int F>
__global__ void gather4_kernel(const int* __restrict__ row_ptr, const int* __restrict__ col,
                               const float4* __restrict__ xs, float4* __restrict__ g, int N) {
    constexpr int FQ = F / 4;
    int idx = blockIdx.x * blockDim.x + threadIdx.x;
    if (idx >= N * FQ) return;
    int n = idx / FQ, q = idx % FQ;
    int beg = row_ptr[n], end = row_ptr[n + 1];
    float4 acc = xs[n * FQ + q];
    int e = beg;
    for (; e + 3 < end; e += 4) {
        int s0 = col[e], s1 = col[e + 1], s2 = col[e + 2], s3 = col[e + 3];
        float4 a = xs[s0 * FQ + q];
        float4 b = xs[s1 * FQ + q];
        float4 c = xs[s2 * FQ + q];
        float4 d = xs[s3 * FQ + q];
        acc.x += a.x + b.x + c.x + d.x;
        acc.y += a.y + b.y + c.y + d.y;
        acc.z += a.z + b.z + c.z + d.z;
        acc.w += a.w + b.w + c.w + d.w;
    }
    for (; e < end; ++e) {
        float4 a = xs[col[e] * FQ + q];
        acc.x += a.x; acc.y += a.y; acc.z += a.z; acc.w += a.w;
    }
    g[n * FQ + q] = acc;
}

template <int FIN, int FOUT, bool PRESCALE_OUT>
__global__ void matmul_kernel(const float* __restrict__ g, const float* __restrict__ W,
                              const float* __restrict__ b, const float* __restrict__ dinv,
                              float* __restrict__ out, int N) {
    int idx = blockIdx.x * blockDim.x + threadIdx.x;
    if (idx >= N * FOUT) return;
    int n = idx / FOUT, f = idx % FOUT;
    float di = dinv[n];
    float acc = 0.f;
    const float* row = g + n * FIN;
#pragma unroll
    for (int k = 0; k < FIN; ++k)
        acc = fmaf(row[k], W[k * FOUT + f], acc);
    float v = fmaxf(di * acc + b[f], 0.f);
    out[idx] = PRESCALE_OUT ? v * di : v;
}

// ---------------- pool + head (atomic-free) ----------------

__global__ void bounds_kernel(const int* __restrict__ batch, int* __restrict__ start,
                              int N, int G) {
    int g = blockIdx.x * blockDim.x + threadIdx.x;
    if (g > G) return;
    if (g == G) { start[G] = N; return; }
    int lo = 0, hi = N;
    while (lo < hi) {
        int mid = (lo + hi) >> 1;
        if (batch[mid] < g) lo = mid + 1; else hi = mid;
    }
    start[g] = lo;
}

__global__ void pool_head_kernel(const float* __restrict__ h, const int* __restrict__ start,
                                 const float* __restrict__ Wfc, const float* __restrict__ bfc,
                                 float* __restrict__ out) {
    __shared__ float part[4][64];
    int g = blockIdx.x;
    int t = threadIdx.x;          // 256
    int f = t & 63, w = t >> 6;
    int s = start[g], e = start[g + 1];
    float acc = 0.f;
    for (int n = s + w; n < e; n += 4)
        acc += h[(size_t)n * 64 + f];
    part[w][f] = acc;
    __syncthreads();
    if (w == 0) {
        float p = part[0][f] + part[1][f] + part[2][f] + part[3][f];
        p /= fmaxf((float)(e - s), 1.0f);
        float l0 = p * Wfc[f * 2 + 0];
        float l1 = p * Wfc[f * 2 + 1];
#pragma unroll
        for (int off = 32; off; off >>= 1) {
            l0 += __shfl_down(l0, off);
            l1 += __shfl_down(l1, off);
        }
        if (f == 0) {
            l0 += bfc[0]; l1 += bfc[1];
            float m   = fmaxf(l0, l1);
            float lse = m + logf(expf(l0 - m) + expf(l1 - m));
            out[g * 2 + 0] = l0 - lse;
            out[g * 2 + 1] = l1 - lse;
        }
    }
}

// ---------------- driver ----------------

extern "C" void kernel_launch(void* const* d_in, const int* in_sizes, int n_in,
                              void* d_out, int out_size, void* d_ws, size_t ws_size,
                              hipStream_t stream) {
    const float* x     = (const float*)d_in[0];
    const int*   src   = (const int*)d_in[1];
    const int*   dst   = (const int*)d_in[2];
    const int*   batch = (const int*)d_in[3];
    const float* W1    = (const float*)d_in[4];
    const float* b1    = (const float*)d_in[5];
    const float* W2    = (const float*)d_in[6];
    const float* b2    = (const float*)d_in[7];
    const float* W3    = (const float*)d_in[8];
    const float* b3    = (const float*)d_in[9];
    const float* Wfc   = (const float*)d_in[10];
    const float* bfc   = (const float*)d_in[11];
    float* out = (float*)d_out;

    const int N = in_sizes[0] / 5;   // 100000
    const int E = in_sizes[1];       // 1600000
    const int G = out_size / 2;      // 1024

    const int nChunks = (E + CHUNK - 1) / CHUNK;        // 1563
    const int NS      = (N + (1 << SLICE_SHIFT) - 1) >> SLICE_SHIFT;   // 13
    const int M       = NS * nChunks;                    // ~20K
    const int Mpad    = (M + 3) & ~3;

    // workspace layout (4B units)
    int* deg      = (int*)d_ws;                   // N
    int* row_ptr  = deg + N;                      // N+4 (uses N+1)
    int* cursor   = row_ptr + N + 4;              // N
    int* col      = cursor + N;                   // E
    int* partials = col + E;                      // 512
    int* start    = partials + 512;               // G+8 (uses G+1)
    int* sliceBeg = start + G + 8;                // 40  (uses NS+1)
    int* cnt      = sliceBeg + 40;                // Mpad
    float* dinv   = (float*)(cnt + Mpad);         // N
    float* A      = dinv + N;                     // N*64
    float* B      = A + (size_t)N * 64;           // N*64
    int* bd       = (int*)A;                      // E   (aliases A; dead before layers)
    int* bs       = bd + E;                       // E
    // total ~ 60 MB

    auto blocks = [](long n) { return (int)((n + BLK - 1) / BLK); };
    const int nb_scan = (N + 1023) / 1024;        // <=256

    // ---- CSR build via hierarchical counting sort ----
    hipMemsetAsync(deg, 0, N * sizeof(int), stream);
    csort_count<<<nChunks, BLK, 0, stream>>>(dst, cnt, E, nChunks, NS);
    csort_scan<<<1, 256, 0, stream>>>(cnt, sliceBeg, M, NS, nChunks, E);
    csort_scatter<<<nChunks, BLK, 0, stream>>>(src, dst, cnt, bd, bs, E, nChunks, NS);
    deg_bucket<<<1024, BLK, 0, stream>>>(bd, sliceBeg, deg, NS);
    scan1_kernel<<<nb_scan, 256, 0, stream>>>(deg, dinv, row_ptr, partials, N);
    scan2_kernel<<<1, 256, 0, stream>>>(partials, nb_scan);
    scan3_kernel<<<blocks(N), BLK, 0, stream>>>(row_ptr, partials, cursor, N, E);
    fill_bucket<<<1024, BLK, 0, stream>>>(bd, bs, sliceBeg, cursor, col, NS);

    // ---- pool boundaries ----
    bounds_kernel<<<blocks(G + 1), BLK, 0, stream>>>(batch, start, N, G);

    // ---- layer 1: x[N,5] -> Xs2 in B[N,16] ----
    prescale1_kernel<<<blocks((long)N * 5), BLK, 0, stream>>>(x, dinv, B, N);              // B = Xs1 [N,5]
    gather_kernel<5><<<blocks((long)N * 5), BLK, 0, stream>>>(row_ptr, col, B, A, N);      // A = g1  [N,5]
    matmul_kernel<5, 16, true><<<blocks((long)N * 16), BLK, 0, stream>>>(A, W1, b1, dinv, B, N);  // B = Xs2 [N,16]

    // ---- layer 2: B[N,16] -> Xs3 in B[N,32] ----
    gather4_kernel<16><<<blocks((long)N * 4), BLK, 0, stream>>>(row_ptr, col,
        (const float4*)B, (float4*)A, N);                                                  // A = g2 [N,16]
    matmul_kernel<16, 32, true><<<blocks((long)N * 32), BLK, 0, stream>>>(A, W2, b2, dinv, B, N); // B = Xs3 [N,32]

    // ---- layer 3: B[N,32] -> out3 in B[N,64] (via A) ----
    gather4_kernel<32><<<blocks((long)N * 8), BLK, 0, stream>>>(row_ptr, col,
        (const float4*)B, (float4*)A, N);                                                  // A = g3 [N,32]
    matmul_kernel<32, 64, false><<<blocks((long)N * 64), BLK, 0, stream>>>(A, W3, b3, dinv, B, N); // B = out3 [N,64]

    // ---- mean pool + head (no atomics) ----
    pool_head_kernel<<<G, 256, 0, stream>>>(B, start, Wfc, bfc, out);
}